// Round 3
// baseline (713.476 us; speedup 1.0000x reference)
//
#include <hip/hip_runtime.h>
#include <hip/hip_bf16.h>

#define LQ     22500
#define SPA_H  58
#define SPA_W  100
#define S_TOT  5800
#define NCAMS  6
#define CDIM   256

typedef __attribute__((ext_vector_type(8))) _Float16 half8;
typedef __attribute__((ext_vector_type(2))) _Float16 half2v;
typedef __attribute__((ext_vector_type(4))) float f32x4;

__device__ __forceinline__ half8 cvt_f32x8(const float* p) {
  f32x4 a = *(const f32x4*)p;
  f32x4 b = *(const f32x4*)(p + 4);
  half8 r;
  r[0] = (_Float16)a.x; r[1] = (_Float16)a.y; r[2] = (_Float16)a.z; r[3] = (_Float16)a.w;
  r[4] = (_Float16)b.x; r[5] = (_Float16)b.y; r[6] = (_Float16)b.z; r[7] = (_Float16)b.w;
  return r;
}

// C[M x N] = A[M x 256] @ W[N x 256]^T + bias.
// A_F16: A is f16 (else f32, converted on load). W, bias always f32.
// OUT_MODE: 0 = f32 out, 2 = f16 out.
template<int N, bool A_F16, int OUT_MODE>
__global__ __launch_bounds__(256) void gemm_xwt(
    const void* __restrict__ Av, const float* __restrict__ W,
    const float* __restrict__ bias, void* __restrict__ Cv, int M) {
  constexpr int K = CDIM;
  constexpr int NT = N / 64;           // 16-col tiles per wave (4 waves/block)
  const int lane = threadIdx.x & 63;
  const int wave = threadIdx.x >> 6;
  const int m15  = lane & 15;
  const int quad = lane >> 4;
  const int row  = blockIdx.x * 16 + m15;
  const int rowc = row < M ? row : M - 1;
  const int colbase = wave * (N / 4);

  f32x4 acc[NT];
#pragma unroll
  for (int t = 0; t < NT; ++t) acc[t] = (f32x4){0.f, 0.f, 0.f, 0.f};

#pragma unroll
  for (int kk = 0; kk < K; kk += 32) {
    const int ko = kk + quad * 8;
    half8 a;
    if (A_F16) a = *(const half8*)((const _Float16*)Av + (size_t)rowc * K + ko);
    else       a = cvt_f32x8((const float*)Av + (size_t)rowc * K + ko);
#pragma unroll
    for (int t = 0; t < NT; ++t) {
      const int col = colbase + t * 16 + m15;
      half8 b = cvt_f32x8(W + (size_t)col * K + ko);
      acc[t] = __builtin_amdgcn_mfma_f32_16x16x32_f16(a, b, acc[t], 0, 0, 0);
    }
  }

  const int orow = blockIdx.x * 16 + quad * 4;
#pragma unroll
  for (int t = 0; t < NT; ++t) {
    const int col = colbase + t * 16 + m15;
    const float bv = bias[col];
#pragma unroll
    for (int i = 0; i < 4; ++i) {
      const int r = orow + i;
      if (r < M) {
        const float v = acc[t][i] + bv;
        if (OUT_MODE == 0) ((float*)Cv)[(size_t)r * N + col] = v;
        else               ((_Float16*)Cv)[(size_t)r * N + col] = (_Float16)v;
      }
    }
  }
}

// One block per query. thread t: head h = t>>4, channels cc=(t&15)*2, cc+1.
__global__ __launch_bounds__(128) void sampler(
    const _Float16* __restrict__ vp,        // (6, 5800, 256) f16 value_proj
    const _Float16* __restrict__ offq,      // (LQ, 128) f16
    const _Float16* __restrict__ awq,       // (LQ, 64) f16
    const float* __restrict__ ref,          // f32 (6, 1, LQ, 4, 2)
    const int* __restrict__ bev,            // int32 (6, 1, LQ, 4)
    _Float16* __restrict__ slots)           // (LQ, 256) f16
{
  const int q = blockIdx.x;
  const int t = threadIdx.x;
  const int h = t >> 4;
  const int cc = (t & 15) * 2;

  __shared__ float s_aw[64];
  __shared__ float s_off[128];
  __shared__ float s_ref[48];
  __shared__ int   s_vis[6];

  if (t < 64) s_aw[t] = (float)awq[(size_t)q * 64 + t];
  s_off[t] = (float)offq[(size_t)q * 128 + t] * ((t & 1) ? (1.f / 58.f) : (1.f / 100.f));
  if (t < 48) s_ref[t] = ref[(size_t)(t >> 3) * (LQ * 8) + (size_t)q * 8 + (t & 7)];
  if (t < 6) {
    const int* bm = bev + (size_t)t * (LQ * 4) + (size_t)q * 4;
    s_vis[t] = (bm[0] + bm[1] + bm[2] + bm[3]) > 0 ? 1 : 0;
  }
  __syncthreads();

  // per-head softmax over the 8 points (redundant across the 16 lanes of a head)
  float w8[8];
  {
    float m = -1e30f;
#pragma unroll
    for (int p = 0; p < 8; ++p) m = fmaxf(m, s_aw[h * 8 + p]);
    float s = 0.f;
#pragma unroll
    for (int p = 0; p < 8; ++p) { w8[p] = __expf(s_aw[h * 8 + p] - m); s += w8[p]; }
    const float inv = 1.f / s;
#pragma unroll
    for (int p = 0; p < 8; ++p) w8[p] *= inv;
  }

  int cnt = 0;
#pragma unroll
  for (int c = 0; c < 6; ++c) cnt += s_vis[c];
  const float invc = 1.f / (float)(cnt > 0 ? cnt : 1);

  float a0 = 0.f, a1 = 0.f;
#pragma unroll
  for (int cam = 0; cam < NCAMS; ++cam) {
    if (!s_vis[cam]) continue;
    const _Float16* vpc = vp + (size_t)cam * (S_TOT * CDIM) + h * 32 + cc;
#pragma unroll
    for (int p = 0; p < 8; ++p) {
      const int z = p & 3;
      const float lx = s_ref[cam * 8 + z * 2 + 0] + s_off[(h * 8 + p) * 2 + 0];
      const float ly = s_ref[cam * 8 + z * 2 + 1] + s_off[(h * 8 + p) * 2 + 1];
      const float x = lx * 100.f - 0.5f;
      const float y = ly * 58.f - 0.5f;
      const float x0f = floorf(x), y0f = floorf(y);
      const float fx = x - x0f, fy = y - y0f;
      const int x0 = (int)x0f, y0 = (int)y0f;
      const float wgt = w8[p];
      const float w00 = (1.f - fy) * (1.f - fx) * wgt;
      const float w01 = (1.f - fy) * fx * wgt;
      const float w10 = fy * (1.f - fx) * wgt;
      const float w11 = fy * fx * wgt;
      const bool xv0 = (x0 >= 0) && (x0 < SPA_W);
      const bool xv1 = (x0 + 1 >= 0) && (x0 + 1 < SPA_W);
      if (y0 >= 0 && y0 < SPA_H) {
        const _Float16* rowp = vpc + (size_t)(y0 * SPA_W) * CDIM;
        if (xv0) { half2v v = *(const half2v*)(rowp + (size_t)x0 * CDIM);
                   a0 = fmaf(w00, (float)v.x, a0); a1 = fmaf(w00, (float)v.y, a1); }
        if (xv1) { half2v v = *(const half2v*)(rowp + (size_t)(x0 + 1) * CDIM);
                   a0 = fmaf(w01, (float)v.x, a0); a1 = fmaf(w01, (float)v.y, a1); }
      }
      if (y0 + 1 >= 0 && y0 + 1 < SPA_H) {
        const _Float16* rowp = vpc + (size_t)((y0 + 1) * SPA_W) * CDIM;
        if (xv0) { half2v v = *(const half2v*)(rowp + (size_t)x0 * CDIM);
                   a0 = fmaf(w10, (float)v.x, a0); a1 = fmaf(w10, (float)v.y, a1); }
        if (xv1) { half2v v = *(const half2v*)(rowp + (size_t)(x0 + 1) * CDIM);
                   a0 = fmaf(w11, (float)v.x, a0); a1 = fmaf(w11, (float)v.y, a1); }
      }
    }
  }
  half2v o; o.x = (_Float16)(a0 * invc); o.y = (_Float16)(a1 * invc);
  *(half2v*)(slots + (size_t)q * CDIM + h * 32 + cc) = o;
}

extern "C" void kernel_launch(void* const* d_in, const int* in_sizes, int n_in,
                              void* d_out, int out_size, void* d_ws, size_t ws_size,
                              hipStream_t stream) {
  const float* query  = (const float*)d_in[0];
  const float* refpts = (const float*)d_in[1];
  const int*   bev    = (const int*)d_in[2];
  const float* value  = (const float*)d_in[3];
  const float* W_off  = (const float*)d_in[4];
  const float* b_off  = (const float*)d_in[5];
  const float* W_attn = (const float*)d_in[6];
  const float* b_attn = (const float*)d_in[7];
  const float* W_val  = (const float*)d_in[8];
  const float* b_val  = (const float*)d_in[9];
  const float* W_out  = (const float*)d_in[10];
  const float* b_out  = (const float*)d_in[11];

  char* ws = (char*)d_ws;
  _Float16* vp    = (_Float16*)(ws + 0);          // 34800*256*2 = 17,817,600
  _Float16* offq  = (_Float16*)(ws + 17817600);   // 22500*128*2 =  5,760,000
  _Float16* awq   = (_Float16*)(ws + 23577600);   // 22500*64*2  =  2,880,000
  _Float16* slots = (_Float16*)(ws + 26457600);   // 22500*256*2 = 11,520,000
                                                  // total ws use: 37,977,600 B

  // value projection: (6*5800) x 256, f16 out
  gemm_xwt<256, false, 2><<<34800 / 16, 256, 0, stream>>>(value, W_val, b_val, vp, 34800);
  // query-side projections: 22500 x {128, 64}, f16 out
  const int qblocks = (LQ + 15) / 16;
  gemm_xwt<128, false, 2><<<qblocks, 256, 0, stream>>>(query, W_off,  b_off,  offq, LQ);
  gemm_xwt<64,  false, 2><<<qblocks, 256, 0, stream>>>(query, W_attn, b_attn, awq,  LQ);

  sampler<<<LQ, 128, 0, stream>>>(vp, offq, awq, refpts, bev, slots);

  // output projection: reads f16 slots, writes f32 d_out
  gemm_xwt<256, true, 0><<<qblocks, 256, 0, stream>>>(slots, W_out, b_out, d_out, LQ);
}

// Round 4
// 370.909 us; speedup vs baseline: 1.9236x; 1.9236x over previous
//
#include <hip/hip_runtime.h>

#define LQ     22500
#define SPA_H  58
#define SPA_W  100
#define S_TOT  5800
#define NCAMS  6
#define CDIM   256

typedef __attribute__((ext_vector_type(8))) _Float16 half8;
typedef __attribute__((ext_vector_type(4))) float f32x4;

__device__ __forceinline__ half8 cvt_f32x8(const float* p) {
  f32x4 a = *(const f32x4*)p;
  f32x4 b = *(const f32x4*)(p + 4);
  half8 r;
  r[0] = (_Float16)a.x; r[1] = (_Float16)a.y; r[2] = (_Float16)a.z; r[3] = (_Float16)a.w;
  r[4] = (_Float16)b.x; r[5] = (_Float16)b.y; r[6] = (_Float16)b.z; r[7] = (_Float16)b.w;
  return r;
}

// One pass: convert W_val/W_out to f16, build concatenated [W_off;W_attn] f16,
// and the concatenated f32 bias for the fused query GEMM.
__global__ __launch_bounds__(256) void cvt_weights_all(
    const float* __restrict__ Wv, const float* __restrict__ Wo,
    const float* __restrict__ Wf, const float* __restrict__ Wa,
    const float* __restrict__ bf, const float* __restrict__ ba,
    _Float16* __restrict__ dst, float* __restrict__ biascat) {
  const int i = blockIdx.x * 256 + threadIdx.x;
  if (i < 192) biascat[i] = (i < 128) ? bf[i] : ba[i - 128];
  if (i >= 180224) return;
  float v;
  if (i < 65536)       v = Wv[i];
  else if (i < 131072) v = Wo[i - 65536];
  else { const int j = i - 131072; v = (j < 32768) ? Wf[j] : Wa[j - 32768]; }
  dst[i] = (_Float16)v;
}

// C[M x N] = A[M x 256] @ W[N x 256]^T + bias.  64-row M-tile, 4 waves own
// disjoint column ranges, B-fragments reused across 4 row-tiles.
// A_F16: A f16 else f32 (inline cvt). W f16. OUT_MODE: 0=f32, 2=f16.
template<int N, bool A_F16, int OUT_MODE>
__global__ __launch_bounds__(256, 2) void gemm64(
    const void* __restrict__ Av, const _Float16* __restrict__ W,
    const float* __restrict__ bias, void* __restrict__ Cv, int M) {
  constexpr int K  = CDIM;
  constexpr int NT = (N / 4) / 16;
  const int lane = threadIdx.x & 63;
  const int wave = threadIdx.x >> 6;
  const int m15  = lane & 15;
  const int quad = lane >> 4;
  const int rowbase = blockIdx.x * 64;
  const int colbase = wave * (N / 4);

  f32x4 acc[4][NT];
#pragma unroll
  for (int rt = 0; rt < 4; ++rt)
#pragma unroll
    for (int t = 0; t < NT; ++t) acc[rt][t] = (f32x4){0.f, 0.f, 0.f, 0.f};

#pragma unroll
  for (int kk = 0; kk < K; kk += 32) {
    const int ko = kk + quad * 8;
    half8 a[4], b[NT];
#pragma unroll
    for (int rt = 0; rt < 4; ++rt) {
      int row = rowbase + rt * 16 + m15;
      row = row < M ? row : M - 1;
      if (A_F16) a[rt] = *(const half8*)((const _Float16*)Av + (size_t)row * K + ko);
      else       a[rt] = cvt_f32x8((const float*)Av + (size_t)row * K + ko);
    }
#pragma unroll
    for (int t = 0; t < NT; ++t)
      b[t] = *(const half8*)(W + (size_t)(colbase + t * 16 + m15) * K + ko);
#pragma unroll
    for (int t = 0; t < NT; ++t)
#pragma unroll
      for (int rt = 0; rt < 4; ++rt)
        acc[rt][t] = __builtin_amdgcn_mfma_f32_16x16x32_f16(a[rt], b[t], acc[rt][t], 0, 0, 0);
  }

#pragma unroll
  for (int rt = 0; rt < 4; ++rt) {
    const int orow = rowbase + rt * 16 + quad * 4;
#pragma unroll
    for (int t = 0; t < NT; ++t) {
      const int col = colbase + t * 16 + m15;
      const float bv = bias[col];
#pragma unroll
      for (int i = 0; i < 4; ++i) {
        const int r = orow + i;
        if (r < M) {
          const float v = acc[rt][t][i] + bv;
          if (OUT_MODE == 0) ((float*)Cv)[(size_t)r * N + col] = v;
          else               ((_Float16*)Cv)[(size_t)r * N + col] = (_Float16)v;
        }
      }
    }
  }
}

// 8 queries/block of 128. Thread: ql=t>>4, s=t&15, head h=s>>1, 16 channels.
__global__ __launch_bounds__(128) void sampler(
    const _Float16* __restrict__ vp,     // (6, 5800, 256) f16
    const _Float16* __restrict__ qproj,  // (LQ, 192) f16: [0,128)=off, [128,192)=attn
    const float* __restrict__ ref,       // f32 (6, 1, LQ, 4, 2)
    const int* __restrict__ bev,         // int32 (6, 1, LQ, 4)
    _Float16* __restrict__ slots)        // (LQ, 256) f16
{
  const int t  = threadIdx.x;
  const int ql = t >> 4;
  const int s  = t & 15;
  const int h  = s >> 1;
  const int hf = s & 1;
  const int q  = blockIdx.x * 8 + ql;
  const bool qok = q < LQ;

  __shared__ float s_off[8][128];
  __shared__ float s_aw[8][64];
  __shared__ float s_ref[8][48];
  __shared__ int   s_vis[8][6];

  if (s < 6) s_vis[ql][s] = 0;
  if (qok) {
    const _Float16* qp = qproj + (size_t)q * 192;
#pragma unroll
    for (int rep = 0; rep < 12; ++rep) {
      const int j = s + rep * 16;
      const float v = (float)qp[j];
      if (j < 128) s_off[ql][j] = v * ((j & 1) ? (1.f / 58.f) : (1.f / 100.f));
      else         s_aw[ql][j - 128] = v;
    }
#pragma unroll
    for (int rep = 0; rep < 3; ++rep) {
      const int k = s + rep * 16;
      s_ref[ql][k] = ref[((size_t)(k >> 3) * LQ + q) * 8 + (k & 7)];
    }
    if (s < 6) {
      const int* bm = bev + ((size_t)s * LQ + q) * 4;
      s_vis[ql][s] = (bm[0] + bm[1] + bm[2] + bm[3]) > 0 ? 1 : 0;
    }
  }
  __syncthreads();

  // per-head softmax (redundant across the 2 lanes of a head)
  float w8[8];
  {
    float m = -1e30f;
#pragma unroll
    for (int p = 0; p < 8; ++p) m = fmaxf(m, s_aw[ql][h * 8 + p]);
    float ssum = 0.f;
#pragma unroll
    for (int p = 0; p < 8; ++p) { w8[p] = __expf(s_aw[ql][h * 8 + p] - m); ssum += w8[p]; }
    const float inv = 1.f / ssum;
#pragma unroll
    for (int p = 0; p < 8; ++p) w8[p] *= inv;
  }

  int cnt = 0;
#pragma unroll
  for (int c = 0; c < 6; ++c) cnt += s_vis[ql][c];
  const float invc = 1.f / (float)(cnt > 0 ? cnt : 1);

  float acc[16];
#pragma unroll
  for (int i = 0; i < 16; ++i) acc[i] = 0.f;

  const int chbase = h * 32 + hf * 16;

#pragma unroll
  for (int cam = 0; cam < NCAMS; ++cam) {
    if (!s_vis[ql][cam]) continue;
    const _Float16* vpc = vp + (size_t)cam * (S_TOT * CDIM) + chbase;
#pragma unroll
    for (int p = 0; p < 8; ++p) {
      const int z = p & 3;
      const float lx = s_ref[ql][cam * 8 + z * 2 + 0] + s_off[ql][(h * 8 + p) * 2 + 0];
      const float ly = s_ref[ql][cam * 8 + z * 2 + 1] + s_off[ql][(h * 8 + p) * 2 + 1];
      const float x = lx * 100.f - 0.5f;
      const float y = ly * 58.f - 0.5f;
      const float x0f = floorf(x), y0f = floorf(y);
      const float fx = x - x0f, fy = y - y0f;
      const int x0 = (int)x0f, y0 = (int)y0f;
      const float wgt = w8[p];
      const float w00 = (1.f - fy) * (1.f - fx) * wgt;
      const float w01 = (1.f - fy) * fx * wgt;
      const float w10 = fy * (1.f - fx) * wgt;
      const float w11 = fy * fx * wgt;
      const bool xv0 = (x0 >= 0) && (x0 < SPA_W);
      const bool xv1 = (x0 + 1 >= 0) && (x0 + 1 < SPA_W);
#pragma unroll
      for (int dy = 0; dy < 2; ++dy) {
        const int yy = y0 + dy;
        if (yy < 0 || yy >= SPA_H) continue;
        const _Float16* rowp = vpc + (size_t)(yy * SPA_W) * CDIM;
        const float wl = dy ? w10 : w00;
        const float wr = dy ? w11 : w01;
        if (xv0) {
          const _Float16* tp = rowp + (size_t)x0 * CDIM;
          half8 v0 = *(const half8*)tp;
          half8 v1 = *(const half8*)(tp + 8);
#pragma unroll
          for (int i = 0; i < 8; ++i) acc[i]     = fmaf(wl, (float)v0[i], acc[i]);
#pragma unroll
          for (int i = 0; i < 8; ++i) acc[8 + i] = fmaf(wl, (float)v1[i], acc[8 + i]);
        }
        if (xv1) {
          const _Float16* tp = rowp + (size_t)(x0 + 1) * CDIM;
          half8 v0 = *(const half8*)tp;
          half8 v1 = *(const half8*)(tp + 8);
#pragma unroll
          for (int i = 0; i < 8; ++i) acc[i]     = fmaf(wr, (float)v0[i], acc[i]);
#pragma unroll
          for (int i = 0; i < 8; ++i) acc[8 + i] = fmaf(wr, (float)v1[i], acc[8 + i]);
        }
      }
    }
  }

  if (qok) {
    half8 o0, o1;
#pragma unroll
    for (int i = 0; i < 8; ++i) { o0[i] = (_Float16)(acc[i] * invc); o1[i] = (_Float16)(acc[8 + i] * invc); }
    _Float16* sp = slots + (size_t)q * CDIM + chbase;
    *(half8*)sp = o0;
    *(half8*)(sp + 8) = o1;
  }
}

extern "C" void kernel_launch(void* const* d_in, const int* in_sizes, int n_in,
                              void* d_out, int out_size, void* d_ws, size_t ws_size,
                              hipStream_t stream) {
  const float* query  = (const float*)d_in[0];
  const float* refpts = (const float*)d_in[1];
  const int*   bev    = (const int*)d_in[2];
  const float* value  = (const float*)d_in[3];
  const float* W_off  = (const float*)d_in[4];
  const float* b_off  = (const float*)d_in[5];
  const float* W_attn = (const float*)d_in[6];
  const float* b_attn = (const float*)d_in[7];
  const float* W_val  = (const float*)d_in[8];
  const float* b_val  = (const float*)d_in[9];
  const float* W_out  = (const float*)d_in[10];
  const float* b_out  = (const float*)d_in[11];

  char* ws = (char*)d_ws;
  _Float16* Wv_h    = (_Float16*)(ws + 0);        // 65536 f16
  _Float16* Wo_h    = (_Float16*)(ws + 131072);   // 65536 f16
  _Float16* Wcat_h  = (_Float16*)(ws + 262144);   // 49152 f16 (end 360448)
  float*    biascat = (float*)   (ws + 360448);   // 192 f32 (end 361216)
  _Float16* vp      = (_Float16*)(ws + 361216);   // 34800*256 f16 = 17,817,600
  _Float16* qproj   = (_Float16*)(ws + 18178816); // 22500*192 f16 =  8,640,000
  _Float16* slots   = (_Float16*)(ws + 26818816); // 22500*256 f16 = 11,520,000
                                                  // total: 38,338,816 B

  cvt_weights_all<<<704, 256, 0, stream>>>(W_val, W_out, W_off, W_attn,
                                           b_off, b_attn, Wv_h, biascat);

  // value projection: 34800 x 256
  gemm64<256, false, 2><<<(34800 + 63) / 64, 256, 0, stream>>>(value, Wv_h, b_val, vp, 34800);
  // fused query projection: 22500 x 192 (off ++ attn)
  gemm64<192, false, 2><<<(LQ + 63) / 64, 256, 0, stream>>>(query, Wcat_h, biascat, qproj, LQ);

  sampler<<<(LQ + 7) / 8, 128, 0, stream>>>(vp, qproj, refpts, bev, slots);

  // output projection: f16 slots -> f32 d_out
  gemm64<256, true, 0><<<(LQ + 63) / 64, 256, 0, stream>>>(slots, Wo_h, b_out, d_out, LQ);
}